// Round 2
// baseline (1872.512 us; speedup 1.0000x reference)
//
#include <hip/hip_runtime.h>

#define E_ 256
#define H_ 512
#define V_ 32000
#define T_ 32
#define LGRID 250   // logits blocks: 250 * 128 cols = 32000
#define VC_ 128     // vocab chunk per logits block

typedef short s16x8 __attribute__((ext_vector_type(8)));
typedef float f32x4 __attribute__((ext_vector_type(4)));
typedef int   i32x4 __attribute__((ext_vector_type(4)));

union US8 { i32x4 i; s16x8 s; };

static __device__ __forceinline__ f32x4 mfma16(s16x8 a, s16x8 b, f32x4 c){
  return __builtin_amdgcn_mfma_f32_16x16x32_bf16(a, b, c, 0, 0, 0);
}

// round-to-nearest-even bf16 "hi" bits live in top 16 after this bias add
static __device__ __forceinline__ unsigned rne(unsigned u){
  return u + 0x7FFFu + ((u >> 16) & 1u);
}

static __device__ __forceinline__ void split_f(float f, unsigned short &hs, unsigned short &ls){
  unsigned r = rne(__float_as_uint(f));
  hs = (unsigned short)(r >> 16);
  float fh = __uint_as_float(r & 0xFFFF0000u);
  unsigned r2 = rne(__float_as_uint(f - fh));
  ls = (unsigned short)(r2 >> 16);
}

// 8 consecutive f32 -> bf16 hi (RNE) + bf16 of residual
static __device__ __forceinline__ void split8(f32x4 a0, f32x4 a1, s16x8 &hi, s16x8 &lo){
  float f[8]; unsigned r[8];
  #pragma unroll
  for (int j=0;j<4;j++){ f[j] = a0[j]; f[4+j] = a1[j]; }
  #pragma unroll
  for (int j=0;j<8;j++) r[j] = rne(__float_as_uint(f[j]));
  US8 Hh, Ll;
  #pragma unroll
  for (int p=0;p<4;p++) Hh.i[p] = (int)__builtin_amdgcn_perm(r[2*p+1], r[2*p], 0x07060302u);
  unsigned d[8];
  #pragma unroll
  for (int j=0;j<8;j++) d[j] = rne(__float_as_uint(f[j] - __uint_as_float(r[j] & 0xFFFF0000u)));
  #pragma unroll
  for (int p=0;p<4;p++) Ll.i[p] = (int)__builtin_amdgcn_perm(d[2*p+1], d[2*p], 0x07060302u);
  hi = Hh.s; lo = Ll.s;
}

// ---------------------------------------------------------------------------
// init: xh x-part = split(features); xh h-part = 0.   grid 128 x 256
// xh layout: [64 batches][768] shorts, k 0..255 = x, k 256..767 = h
// ---------------------------------------------------------------------------
__global__ __launch_bounds__(256) void init_kernel(
    const float* __restrict__ feat,
    unsigned short* __restrict__ xh_hi, unsigned short* __restrict__ xh_lo)
{
  const int blk = blockIdx.x, t = threadIdx.x;
  if (blk < 64){
    unsigned short hs, lsv; split_f(feat[blk*E_ + t], hs, lsv);
    xh_hi[blk*768 + t] = hs; xh_lo[blk*768 + t] = lsv;
  } else {
    int b = blk - 64;
    ((unsigned*)(xh_hi + b*768 + 256))[t] = 0u;
    ((unsigned*)(xh_lo + b*768 + 256))[t] = 0u;
  }
}

// ---------------------------------------------------------------------------
// gates: gates = xh @ [Wih|Whh]^T + biases; LSTM pointwise; h -> xh, c -> ws.
// grid 64 x 256. Block owns 32 interleaved cols c = blk*32 + lc, where
// c = 4*u + gate (u = hidden unit, gate in {i,f,g,o} = W row (gate*512+u)).
// K=768 split across 4 waves (192 each), partial C reduced through LDS.
// ---------------------------------------------------------------------------
__global__ __launch_bounds__(256) void gates_kernel(
    const float* __restrict__ Wih, const float* __restrict__ Whh,
    const float* __restrict__ bih, const float* __restrict__ bhh,
    unsigned short* __restrict__ xh_hi, unsigned short* __restrict__ xh_lo,
    float* __restrict__ c_state, int s)
{
  const int blk = blockIdx.x, t = threadIdx.x;
  const int wv = t >> 6, lq = (t >> 4) & 3, ln = t & 15;
  __shared__ float red[8192];     // 4wv x 2g x 4m x 4lq x 16ln x f32x4
  __shared__ float gbuf[2112];    // 64 batches x 32 cols, stride 33

  s16x8 Agh[4][6], Agl[4][6];
  #pragma unroll
  for (int m=0;m<4;m++)
    #pragma unroll
    for (int kt=0;kt<6;kt++){
      int br = m*16 + ln;
      int k  = 192*wv + 32*kt + 8*lq;
      Agh[m][kt] = *(const s16x8*)(xh_hi + br*768 + k);
      Agl[m][kt] = *(const s16x8*)(xh_lo + br*768 + k);
    }

  f32x4 acc[2][4];
  #pragma unroll
  for (int g=0;g<2;g++)
    #pragma unroll
    for (int m=0;m<4;m++){ f32x4 z = {0.f,0.f,0.f,0.f}; acc[g][m] = z; }

  #pragma unroll
  for (int g=0;g<2;g++){
    int c = blk*32 + g*16 + ln;
    const float* pih = Wih + (size_t)((c&3)*512 + (c>>2))*256;
    const float* phh = Whh + (size_t)((c&3)*512 + (c>>2))*512;
    #pragma unroll
    for (int kt=0;kt<6;kt++){
      int kg = 192*wv + 32*kt;
      int k  = kg + 8*lq;
      const float* p = (kg < 256) ? (pih + k) : (phh + (k - 256));
      f32x4 a0 = *(const f32x4*)p;
      f32x4 a1 = *(const f32x4*)(p + 4);
      s16x8 Bh, Bl; split8(a0, a1, Bh, Bl);
      #pragma unroll
      for (int m=0;m<4;m++){
        acc[g][m] = mfma16(Agh[m][kt], Bh, acc[g][m]);
        acc[g][m] = mfma16(Agh[m][kt], Bl, acc[g][m]);
        acc[g][m] = mfma16(Agl[m][kt], Bh, acc[g][m]);
      }
    }
  }
  #pragma unroll
  for (int g=0;g<2;g++)
    #pragma unroll
    for (int m=0;m<4;m++){
      int f4 = (((wv*2+g)*4+m)*4+lq)*16 + ln;
      *(f32x4*)(red + f4*4) = acc[g][m];
    }
  __syncthreads();
  #pragma unroll
  for (int g=0;g<2;g++){
    f32x4 v4 = {0.f,0.f,0.f,0.f};
    #pragma unroll
    for (int ww=0;ww<4;ww++){
      int f4 = (((ww*2+g)*4+wv)*4+lq)*16 + ln;
      v4 += *(const f32x4*)(red + f4*4);
    }
    int c = blk*32 + g*16 + ln;
    int row = (c&3)*512 + (c>>2);
    float bias = bih[row] + bhh[row];
    #pragma unroll
    for (int r=0;r<4;r++)
      gbuf[(wv*16 + lq*4 + r)*33 + g*16 + ln] = v4[r] + bias;
  }
  __syncthreads();
  #pragma unroll
  for (int rep=0;rep<2;rep++){
    int p = rep*256 + t;
    int b = p >> 3, ul = p & 7;
    float gi = gbuf[b*33 + ul*4 + 0];
    float gf = gbuf[b*33 + ul*4 + 1];
    float gg = gbuf[b*33 + ul*4 + 2];
    float go = gbuf[b*33 + ul*4 + 3];
    int u = blk*8 + ul;
    float cp = (s <= 1) ? 0.f : c_state[b*512 + u];  // ref restarts state after feature step
    float si = 1.f/(1.f + __expf(-gi));
    float sf = 1.f/(1.f + __expf(-gf));
    float so = 1.f/(1.f + __expf(-go));
    float cn = sf*cp + si*tanhf(gg);
    c_state[b*512 + u] = cn;
    float hv = so*tanhf(cn);
    unsigned short hs, lsv; split_f(hv, hs, lsv);
    xh_hi[b*768 + 256 + u] = hs;
    xh_lo[b*768 + 256 + u] = lsv;
  }
}

// ---------------------------------------------------------------------------
// logits: block blk owns vocab cols [blk*128, blk*128+128).
//  1) rescale out row s-2 in place by invs (from final(s-1))        (s>=2)
//  2) logits = h @ Wfc^T + bfc via bf16x3 MFMA (K=512, 128/wave)
//  3) exp -> LDS slab + per-block sum/max/argmax partials -> ws
//  4) dump raw exp slab to out row s-1 (coalesced)                  (s>=1)
// grid 250 x 256
// ---------------------------------------------------------------------------
__global__ __launch_bounds__(256) void logits_kernel(
    const float* __restrict__ Wfc, const float* __restrict__ bfc,
    const unsigned short* __restrict__ xh_hi, const unsigned short* __restrict__ xh_lo,
    float* __restrict__ out, float* __restrict__ psum, float* __restrict__ pmaxv,
    int* __restrict__ pmaxi, const float* __restrict__ invs, int s)
{
  const int blk = blockIdx.x, t = threadIdx.x;
  const int wv = t >> 6, lq = (t >> 4) & 3, ln = t & 15;
  __shared__ float red[8192];
  __shared__ float slab[8192];    // [64 b][128 v] raw exp

  if (s >= 2){
    #pragma unroll 4
    for (int i=0;i<32;i++){
      int e = i*256 + t; int b = e >> 7, v = e & 127;
      out[((size_t)b*T_ + (s-2))*V_ + blk*VC_ + v] *= invs[b];
    }
  }

  s16x8 Ah[4][4], Al[4][4];
  #pragma unroll
  for (int m=0;m<4;m++)
    #pragma unroll
    for (int ks=0;ks<4;ks++){
      int br = m*16 + ln;
      int k  = 128*wv + 32*ks + 8*lq;
      Ah[m][ks] = *(const s16x8*)(xh_hi + br*768 + 256 + k);
      Al[m][ks] = *(const s16x8*)(xh_lo + br*768 + 256 + k);
    }

  f32x4 rsum = {0.f,0.f,0.f,0.f};
  f32x4 rmax = {-1e30f,-1e30f,-1e30f,-1e30f};
  i32x4 ridx = {0x7fffffff,0x7fffffff,0x7fffffff,0x7fffffff};

  for (int G=0;G<4;G++){
    f32x4 acc[2][4];
    #pragma unroll
    for (int g=0;g<2;g++)
      #pragma unroll
      for (int m=0;m<4;m++){ f32x4 z = {0.f,0.f,0.f,0.f}; acc[g][m] = z; }

    #pragma unroll
    for (int g=0;g<2;g++){
      int vt = G*2 + g;
      const float* wp = Wfc + (size_t)(blk*VC_ + vt*16 + ln)*512 + 128*wv + 8*lq;
      #pragma unroll
      for (int ks=0;ks<4;ks++){
        f32x4 a0 = *(const f32x4*)(wp + 32*ks);
        f32x4 a1 = *(const f32x4*)(wp + 32*ks + 4);
        s16x8 Bh, Bl; split8(a0, a1, Bh, Bl);
        #pragma unroll
        for (int m=0;m<4;m++){
          acc[g][m] = mfma16(Ah[m][ks], Bh, acc[g][m]);
          acc[g][m] = mfma16(Ah[m][ks], Bl, acc[g][m]);
          acc[g][m] = mfma16(Al[m][ks], Bh, acc[g][m]);
        }
      }
    }
    #pragma unroll
    for (int g=0;g<2;g++)
      #pragma unroll
      for (int m=0;m<4;m++){
        int f4 = (((wv*2+g)*4+m)*4+lq)*16 + ln;
        *(f32x4*)(red + f4*4) = acc[g][m];
      }
    __syncthreads();
    #pragma unroll
    for (int g=0;g<2;g++){
      int vt = G*2+g;
      f32x4 v4 = {0.f,0.f,0.f,0.f};
      #pragma unroll
      for (int ww=0;ww<4;ww++){
        int f4 = (((ww*2+g)*4+wv)*4+lq)*16 + ln;
        v4 += *(const f32x4*)(red + f4*4);
      }
      int vg = blk*VC_ + vt*16 + ln;
      float bias = bfc[vg];
      #pragma unroll
      for (int r=0;r<4;r++){
        float pe = __expf(v4[r] + bias);
        slab[(wv*16 + lq*4 + r)*128 + vt*16 + ln] = pe;
        rsum[r] += pe;
        if (pe > rmax[r]){ rmax[r] = pe; ridx[r] = vg; }  // ascending vg keeps first max
      }
    }
    __syncthreads();
  }

  // combine 16 ln-lanes (same batch quad, disjoint vocab cols)
  #pragma unroll
  for (int d2=1; d2<16; d2<<=1){
    #pragma unroll
    for (int r=0;r<4;r++){
      float os = __shfl_xor(rsum[r], d2, 64);
      float ov = __shfl_xor(rmax[r], d2, 64);
      int   oi = __shfl_xor(ridx[r], d2, 64);
      rsum[r] += os;
      if (ov > rmax[r] || (ov == rmax[r] && oi < ridx[r])){ rmax[r]=ov; ridx[r]=oi; }
    }
  }
  if (ln == 0){
    #pragma unroll
    for (int r=0;r<4;r++){
      int b = wv*16 + lq*4 + r;
      psum [b*256 + blk] = rsum[r];
      pmaxv[b*256 + blk] = rmax[r];
      pmaxi[b*256 + blk] = ridx[r];
    }
  }

  if (s >= 1){   // slab complete (trailing __syncthreads of the G loop)
    #pragma unroll 4
    for (int i=0;i<32;i++){
      int e = i*256 + t; int b = e >> 7, v = e & 127;
      out[((size_t)b*T_ + (s-1))*V_ + blk*VC_ + v] = slab[b*128 + v];
    }
  }
}

// ---------------------------------------------------------------------------
// final: per-batch reduce of 250 partials -> invs + greedy argmax -> embed x.
// grid 128 x 256 (blocks 64..127 only zero the h-part at s==0, matching the
// reference's discard of the feature-step hidden state).
// ---------------------------------------------------------------------------
__global__ __launch_bounds__(256) void final_kernel(
    const float* __restrict__ psum, const float* __restrict__ pmaxv,
    const int* __restrict__ pmaxi, float* __restrict__ invs,
    const float* __restrict__ emb,
    unsigned short* __restrict__ xh_hi, unsigned short* __restrict__ xh_lo, int s)
{
  const int blk = blockIdx.x, t = threadIdx.x, wv = t >> 6;
  if (blk >= 64){
    if (s == 0 && blk < 128){
      int b = blk - 64;
      ((unsigned*)(xh_hi + b*768 + 256))[t] = 0u;
      ((unsigned*)(xh_lo + b*768 + 256))[t] = 0u;
    }
    return;
  }
  __shared__ float fin[32];
  float sv = 0.f, mv = -1e30f; int mi = 0x7fffffff;
  if (t < LGRID){ sv = psum[blk*256+t]; mv = pmaxv[blk*256+t]; mi = pmaxi[blk*256+t]; }
  #pragma unroll
  for (int d2=1; d2<64; d2<<=1){
    float os = __shfl_xor(sv, d2, 64);
    float ov = __shfl_xor(mv, d2, 64);
    int   oi = __shfl_xor(mi, d2, 64);
    sv += os;
    if (ov > mv || (ov == mv && oi < mi)){ mv = ov; mi = oi; }
  }
  if ((t & 63) == 0){ fin[wv] = sv; fin[8+wv] = mv; ((int*)fin)[16+wv] = mi; }
  __syncthreads();
  if (t == 0){
    float S = fin[0]+fin[1]+fin[2]+fin[3];
    float M = -1e30f; int I = 0x7fffffff;
    #pragma unroll
    for (int ww=0;ww<4;ww++){
      float vvv = fin[8+ww]; int ii = ((int*)fin)[16+ww];
      if (vvv > M || (vvv == M && ii < I)){ M = vvv; I = ii; }
    }
    invs[blk] = 1.0f/S;
    ((int*)fin)[20] = I;
  }
  __syncthreads();
  int am = ((int*)fin)[20];
  unsigned short hs, lsv; split_f(emb[(size_t)am*E_ + t], hs, lsv);
  xh_hi[blk*768 + t] = hs;
  xh_lo[blk*768 + t] = lsv;
}

// ---------------------------------------------------------------------------
// epilogue: rescale row 30 (step-31 raw exps) and zero row 31. grid 250 x 256
// ---------------------------------------------------------------------------
__global__ __launch_bounds__(256) void epilogue_kernel(
    float* __restrict__ out, const float* __restrict__ invs)
{
  const int blk = blockIdx.x, t = threadIdx.x;
  #pragma unroll 4
  for (int i=0;i<32;i++){
    int e = i*256 + t; int b = e >> 7, v = e & 127;
    out[((size_t)b*T_ + 30)*V_ + blk*VC_ + v] *= invs[b];
    out[((size_t)b*T_ + 31)*V_ + blk*VC_ + v] = 0.f;
  }
}

extern "C" void kernel_launch(void* const* d_in, const int* in_sizes, int n_in,
                              void* d_out, int out_size, void* d_ws, size_t ws_size,
                              hipStream_t stream){
  const float* feat = (const float*)d_in[0];
  // d_in[1] = captions: unused by the reference computation
  const float* emb  = (const float*)d_in[2];
  const float* Wih  = (const float*)d_in[3];
  const float* Whh  = (const float*)d_in[4];
  const float* bih  = (const float*)d_in[5];
  const float* bhh  = (const float*)d_in[6];
  const float* Wfc  = (const float*)d_in[7];
  const float* bfc  = (const float*)d_in[8];
  float* out = (float*)d_out;

  char* ws = (char*)d_ws;                                   // ~513 KB used
  unsigned short* xh_hi = (unsigned short*)(ws);            // 64x768 u16
  unsigned short* xh_lo = (unsigned short*)(ws + 98304);    // 64x768 u16
  float* c_state = (float*)(ws + 196608);                   // 64x512 f32
  float* psum  = (float*)(ws + 327680);                     // [64][256]
  float* pmaxv = (float*)(ws + 393216);                     // [64][256]
  int*   pmaxi = (int*)  (ws + 458752);                     // [64][256]
  float* invs  = (float*)(ws + 524288);                     // [64]

  init_kernel<<<128, 256, 0, stream>>>(feat, xh_hi, xh_lo);
  for (int s = 0; s < T_; ++s){
    gates_kernel<<<64, 256, 0, stream>>>(Wih, Whh, bih, bhh, xh_hi, xh_lo, c_state, s);
    logits_kernel<<<LGRID, 256, 0, stream>>>(Wfc, bfc, xh_hi, xh_lo, out,
                                             psum, pmaxv, pmaxi, invs, s);
    final_kernel<<<128, 256, 0, stream>>>(psum, pmaxv, pmaxi, invs, emb, xh_hi, xh_lo, s);
  }
  epilogue_kernel<<<LGRID, 256, 0, stream>>>(out, invs);
}